// Round 6
// baseline (193.331 us; speedup 1.0000x reference)
//
#include <hip/hip_runtime.h>
#include <hip/hip_bf16.h>
#include <stdint.h>

#define BB 4
#define NN 1024
#define DD 1024
#define HH 16
#define HDIM 64
#define KVHH 4
#define MM (BB * NN)  // 4096 token rows

typedef __hip_bfloat16 bf16;
typedef __attribute__((ext_vector_type(8))) short bf16x8;  // 8 bf16 = 4 VGPR
typedef __attribute__((ext_vector_type(4))) float f32x4;

__device__ __forceinline__ float b2f(unsigned short u) {
  return __uint_as_float(((unsigned)u) << 16);
}
__device__ __forceinline__ unsigned short f2b(float x) {
  bf16 h = __float2bfloat16(x);
  unsigned short u;
  __builtin_memcpy(&u, &h, 2);
  return u;
}
__device__ __forceinline__ f32x4 mfma16(bf16x8 a, bf16x8 b, f32x4 c) {
  return __builtin_amdgcn_mfma_f32_16x16x32_bf16(a, b, c, 0, 0, 0);
}
__device__ __forceinline__ void gl_lds16(const short* g, short* l) {
  __builtin_amdgcn_global_load_lds(
      (const __attribute__((address_space(1))) unsigned*)g,
      (__attribute__((address_space(3))) unsigned*)l, 16, 0, 0);
}

// ---------------------------------------------------------------------------
__global__ __launch_bounds__(256) void cvt_f32_bf16(const float* __restrict__ src,
                                                    short* __restrict__ dst, int n4) {
  int i = blockIdx.x * 256 + threadIdx.x;
  if (i < n4) {
    float4 v = *(const float4*)&src[(size_t)i * 4];
    ushort4 o;
    o.x = f2b(v.x); o.y = f2b(v.y); o.z = f2b(v.z); o.w = f2b(v.w);
    *(ushort4*)&dst[(size_t)i * 4] = o;
  }
}

// ---------------------------------------------------------------------------
// All 4 weight transposes + combined-bias build in one dispatch.
// W (K x N fp32) -> WT (N x K bf16). 64x64 LDS tiles. z==4 builds bias.
// ---------------------------------------------------------------------------
__global__ __launch_bounds__(256) void transpose_all(
    const float* __restrict__ Wq, const float* __restrict__ Wkv,
    const float* __restrict__ Wg, const float* __restrict__ Wo,
    const float* __restrict__ bg, short* __restrict__ WcT,
    short* __restrict__ WoT, float* __restrict__ bias) {
  const int z = blockIdx.z;
  if (z == 4) {  // combined bias: [0,1024)=0, [1024,2048)=bg, [2048,2560)=0
    if (blockIdx.y == 0 && blockIdx.x < 10) {
      int i = blockIdx.x * 256 + threadIdx.x;
      if (i < 2560) bias[i] = (i >= 1024 && i < 2048) ? bg[i - 1024] : 0.f;
    }
    return;
  }
  const float* W;
  short* WT;
  int N = 1024;
  const int K = 1024;
  if (z == 0) { W = Wq; WT = WcT; }
  else if (z == 1) { W = Wg; WT = WcT + 1048576; }
  else if (z == 2) {
    W = Wkv; WT = WcT + 2097152; N = 512;
    if (blockIdx.x >= 8) return;  // uniform early-out, before any sync
  } else { W = Wo; WT = WoT; }

  __shared__ short T[64 * 68];
  const int tid = threadIdx.x;
  const int n0 = blockIdx.x * 64, k0 = blockIdx.y * 64;
  {
    int i0 = tid >> 4, j4 = (tid & 15) * 4;
#pragma unroll
    for (int ii = 0; ii < 4; ++ii) {
      int i = i0 + 16 * ii;
      float4 w = *(const float4*)&W[(size_t)(k0 + i) * N + n0 + j4];
      ushort4 o;
      o.x = f2b(w.x); o.y = f2b(w.y); o.z = f2b(w.z); o.w = f2b(w.w);
      *(ushort4*)&T[i * 68 + j4] = o;
    }
  }
  __syncthreads();
  {
    int n = tid >> 2, k16 = (tid & 3) * 16;
    short tmp[16];
#pragma unroll
    for (int kk = 0; kk < 16; ++kk) tmp[kk] = T[(k16 + kk) * 68 + n];
    short* dst = WT + (size_t)(n0 + n) * K + k0 + k16;
#pragma unroll
    for (int s = 0; s < 16; s += 4) *(ushort4*)&dst[s] = *(const ushort4*)&tmp[s];
  }
}

// ---------------------------------------------------------------------------
// Fused projection GEMM: [q|g|kv] = xb @ WcT^T, 128x128 tile, BK=32, 4 waves,
// DOUBLE-BUFFERED gl_lds staging (1 barrier/iter; prefetch k+1 overlaps
// compute k). Epilogue diverts to compact head-major buffers:
//   q  (col <1024)      -> qc[((b*16+h)*1024+tok)*64+d]
//   g  (1024..2048)     -> gc[((b*16+h)*1024+tok)*64+d]
//   k  (2048..2304)     -> kc[((b*4+kvh)*1024+tok)*64+d]
//   v  (2304..2560)     -> vt[((b*4+kvh)*64+d)*1024+tok]   (transposed)
// ---------------------------------------------------------------------------
__global__ __launch_bounds__(256) void gemm_proj(
    const short* __restrict__ A, const short* __restrict__ WT,
    const float* __restrict__ bias, short* __restrict__ qc,
    short* __restrict__ gc, short* __restrict__ kc, short* __restrict__ vt) {
  __shared__ short As[2][128 * 32];
  __shared__ short Bs[2][128 * 32];
  const int tid = threadIdx.x;
  const int wave = tid >> 6, lane = tid & 63, l15 = lane & 15, quad = lane >> 4;
  const int m0 = blockIdx.y * 128, n0 = blockIdx.x * 128;
  const int wm = (wave & 1) * 64, wn = (wave >> 1) * 64;
  const int arow = tid >> 2, ac = (tid & 3) * 8;
  const short* asrc = A + (size_t)(m0 + arow) * 1024 + ac;
  const short* bsrc = WT + (size_t)(n0 + arow) * 1024 + ac;

  // prologue: stage k0=0 into buffer 0
  gl_lds16(asrc, &As[0][wave * 512]);
  gl_lds16(asrc + 64 * 1024, &As[0][wave * 512 + 2048]);
  gl_lds16(bsrc, &Bs[0][wave * 512]);
  gl_lds16(bsrc + 64 * 1024, &Bs[0][wave * 512 + 2048]);

  f32x4 acc[4][4] = {};
  for (int k = 0; k < 32; ++k) {
    const int cur = k & 1;
    __syncthreads();  // stage(k) landed; iter k-1 LDS reads drained
    if (k < 31) {
      const short* ap = asrc + (k + 1) * 32;
      const short* bp = bsrc + (k + 1) * 32;
      gl_lds16(ap, &As[1 - cur][wave * 512]);
      gl_lds16(ap + 64 * 1024, &As[1 - cur][wave * 512 + 2048]);
      gl_lds16(bp, &Bs[1 - cur][wave * 512]);
      gl_lds16(bp + 64 * 1024, &Bs[1 - cur][wave * 512 + 2048]);
    }
    bf16x8 af[4], bfr[4];
#pragma unroll
    for (int i = 0; i < 4; ++i)
      af[i] = *(const bf16x8*)&As[cur][(wm + 16 * i + l15) * 32 + quad * 8];
#pragma unroll
    for (int j = 0; j < 4; ++j)
      bfr[j] = *(const bf16x8*)&Bs[cur][(wn + 16 * j + l15) * 32 + quad * 8];
#pragma unroll
    for (int i = 0; i < 4; ++i)
#pragma unroll
      for (int j = 0; j < 4; ++j) acc[i][j] = mfma16(af[i], bfr[j], acc[i][j]);
  }
#pragma unroll
  for (int j = 0; j < 4; ++j) {
    int col = n0 + wn + 16 * j + l15;
    float bv = bias[col];
    int reg = col >> 6;  // head-slot 0..39 (uniform across the 16 lanes)
    int d = col & 63;
#pragma unroll
    for (int i = 0; i < 4; ++i) {
#pragma unroll
      for (int r = 0; r < 4; ++r) {
        int row = m0 + wm + 16 * i + quad * 4 + r;
        int b = row >> 10, tok = row & 1023;
        unsigned short v = f2b(acc[i][j][r] + bv);
        if (reg < 16)
          ((unsigned short*)qc)[((size_t)((b * 16 + reg) * 1024 + tok)) * 64 + d] = v;
        else if (reg < 32)
          ((unsigned short*)gc)[((size_t)((b * 16 + reg - 16) * 1024 + tok)) * 64 + d] = v;
        else if (reg < 36)
          ((unsigned short*)kc)[((size_t)((b * 4 + reg - 32) * 1024 + tok)) * 64 + d] = v;
        else
          ((unsigned short*)vt)[((size_t)((b * 4 + reg - 36) * 64 + d)) * 1024 + tok] = v;
      }
    }
  }
}

// ---------------------------------------------------------------------------
// Output-projection GEMM, 64x128 tile, 4 waves = 2x2 of 32x64, double-buffered.
// ---------------------------------------------------------------------------
__global__ __launch_bounds__(256) void gemm_out(
    const short* __restrict__ A, const short* __restrict__ WT,
    float* __restrict__ Cout) {
  __shared__ short As[2][64 * 32];
  __shared__ short Bs[2][128 * 32];
  const int tid = threadIdx.x;
  const int wave = tid >> 6, lane = tid & 63, l15 = lane & 15, quad = lane >> 4;
  const int m0 = blockIdx.y * 64, n0 = blockIdx.x * 128;
  const int wm = (wave & 1) * 32, wn = (wave >> 1) * 64;
  const int arow = tid >> 2, ac = (tid & 3) * 8;
  const short* asrc = A + (size_t)(m0 + arow) * 1024 + ac;
  const short* bsrc = WT + (size_t)(n0 + arow) * 1024 + ac;

  gl_lds16(asrc, &As[0][wave * 512]);
  gl_lds16(bsrc, &Bs[0][wave * 512]);
  gl_lds16(bsrc + 64 * 1024, &Bs[0][wave * 512 + 2048]);

  f32x4 acc[2][4] = {};
  for (int k = 0; k < 32; ++k) {
    const int cur = k & 1;
    __syncthreads();
    if (k < 31) {
      const short* ap = asrc + (k + 1) * 32;
      const short* bp = bsrc + (k + 1) * 32;
      gl_lds16(ap, &As[1 - cur][wave * 512]);
      gl_lds16(bp, &Bs[1 - cur][wave * 512]);
      gl_lds16(bp + 64 * 1024, &Bs[1 - cur][wave * 512 + 2048]);
    }
    bf16x8 af[2], bfr[4];
#pragma unroll
    for (int i = 0; i < 2; ++i)
      af[i] = *(const bf16x8*)&As[cur][(wm + 16 * i + l15) * 32 + quad * 8];
#pragma unroll
    for (int j = 0; j < 4; ++j)
      bfr[j] = *(const bf16x8*)&Bs[cur][(wn + 16 * j + l15) * 32 + quad * 8];
#pragma unroll
    for (int i = 0; i < 2; ++i)
#pragma unroll
      for (int j = 0; j < 4; ++j) acc[i][j] = mfma16(af[i], bfr[j], acc[i][j]);
  }
#pragma unroll
  for (int j = 0; j < 4; ++j) {
    int col = n0 + wn + 16 * j + l15;
#pragma unroll
    for (int i = 0; i < 2; ++i) {
#pragma unroll
      for (int r = 0; r < 4; ++r) {
        int row = m0 + wm + 16 * i + quad * 4 + r;
        Cout[(size_t)row * 1024 + col] = acc[i][j][r];
      }
    }
  }
}

// ---------------------------------------------------------------------------
// MFMA flash attention + gate. S^T formulation, fixed-max softmax, compact
// head-major inputs, swizzled double-buffered K/V staging, swizzled P.
// Block: (qt, b*16+h), 64 q rows, 4 waves; wave owns 16 keys (S) / 16 d (PV).
// ---------------------------------------------------------------------------
__global__ __launch_bounds__(256, 3) void attn_mfma4(
    const short* __restrict__ qc, const short* __restrict__ gc,
    const short* __restrict__ kc, const short* __restrict__ vt,
    unsigned short* __restrict__ gated) {
  __shared__ short Kt[2][64 * 64];
  __shared__ short Vt[2][64 * 64];
  __shared__ short Ps[64 * 64];
  __shared__ float Lpart[4 * 64];
  __shared__ float Lq[64];
  const int tid = threadIdx.x;
  const int w = tid >> 6, lane = tid & 63, l15 = lane & 15, quad = lane >> 4;
  const int qt = blockIdx.x, bh = blockIdx.y, b = bh >> 4, h = bh & 15, kvh = h >> 2;
  const int fs = l15 & 7;                // frag-read swizzle key (row&7)
  const int s0 = (quad ^ fs) * 8;        // slot offset, k-chunk quad
  const int s1 = ((4 + quad) ^ fs) * 8;  // slot offset, k-chunk 4+quad

  // Q B-frags (loop-invariant); qc rows are 128 B apart
  bf16x8 qf[4][2];
#pragma unroll
  for (int jq = 0; jq < 4; ++jq) {
    const short* qp =
        qc + ((size_t)((b * 16 + h) * 1024) + qt * 64 + 16 * jq + l15) * 64 + quad * 8;
    qf[jq][0] = *(const bf16x8*)qp;
    qf[jq][1] = *(const bf16x8*)(qp + 32);
  }

  // staging: lane covers (row = 16w + srow + 8i, chunk = schunk); contiguous 2KB
  const int srow = lane >> 3;
  const int schunk = (lane & 7) ^ srow;
  const short* kstage = kc + ((size_t)((b * 4 + kvh) * 1024) + 16 * w + srow) * 64 + schunk * 8;
  const short* vstage = vt + ((size_t)((b * 4 + kvh) * 64) + 16 * w + srow) * 1024 + schunk * 8;

  f32x4 oacc[4];
  float ls[4];
#pragma unroll
  for (int jq = 0; jq < 4; ++jq) {
    oacc[jq] = (f32x4){0.f, 0.f, 0.f, 0.f};
    ls[jq] = 0.f;
  }

  // P-write slot: uint2 = keys [16w+4quad,+4) -> chunk 2w+(quad>>1), half quad&1
  const int pslot = ((2 * w + (quad >> 1)) ^ fs) * 8 + (quad & 1) * 4;

  // prologue: stage kt=0 into buffer 0
  gl_lds16(kstage, &Kt[0][(16 * w) * 64]);
  gl_lds16(kstage + 512, &Kt[0][(16 * w + 8) * 64]);
  gl_lds16(vstage, &Vt[0][(16 * w) * 64]);
  gl_lds16(vstage + 8192, &Vt[0][(16 * w + 8) * 64]);

  for (int kt = 0; kt < 16; ++kt) {
    const int cur = kt & 1;
    __syncthreads();  // K/V(kt) staged; PV(kt-1) LDS reads done
    // ---- S phase: S^T = K·Q^T, wave owns keys [16w,16w+16)
    bf16x8 kf0 = *(const bf16x8*)&Kt[cur][(16 * w + l15) * 64 + s0];
    bf16x8 kf1 = *(const bf16x8*)&Kt[cur][(16 * w + l15) * 64 + s1];
#pragma unroll
    for (int jq = 0; jq < 4; ++jq) {
      f32x4 st = mfma16(kf0, qf[jq][0], (f32x4){0.f, 0.f, 0.f, 0.f});
      st = mfma16(kf1, qf[jq][1], st);
      float p0 = __expf(st[0] * 0.125f);
      float p1 = __expf(st[1] * 0.125f);
      float p2 = __expf(st[2] * 0.125f);
      float p3 = __expf(st[3] * 0.125f);
      ls[jq] += (p0 + p1) + (p2 + p3);
      uint2 dd;
      dd.x = (unsigned)f2b(p0) | ((unsigned)f2b(p1) << 16);
      dd.y = (unsigned)f2b(p2) | ((unsigned)f2b(p3) << 16);
      *(uint2*)&Ps[(16 * jq + l15) * 64 + pslot] = dd;
    }
    __syncthreads();  // P(kt) visible; K(kt) reads done
    if (kt < 15) {    // prefetch kt+1
      const short* kp = kstage + (size_t)(kt + 1) * 4096;
      const short* vp = vstage + (size_t)(kt + 1) * 64;
      gl_lds16(kp, &Kt[1 - cur][(16 * w) * 64]);
      gl_lds16(kp + 512, &Kt[1 - cur][(16 * w + 8) * 64]);
      gl_lds16(vp, &Vt[1 - cur][(16 * w) * 64]);
      gl_lds16(vp + 8192, &Vt[1 - cur][(16 * w + 8) * 64]);
    }
    // ---- PV phase: wave owns d-subtile w
    bf16x8 vf0 = *(const bf16x8*)&Vt[cur][(16 * w + l15) * 64 + s0];
    bf16x8 vf1 = *(const bf16x8*)&Vt[cur][(16 * w + l15) * 64 + s1];
#pragma unroll
    for (int jq = 0; jq < 4; ++jq) {
      bf16x8 pf0 = *(const bf16x8*)&Ps[(16 * jq + l15) * 64 + s0];
      bf16x8 pf1 = *(const bf16x8*)&Ps[(16 * jq + l15) * 64 + s1];
      oacc[jq] = mfma16(pf0, vf0, oacc[jq]);
      oacc[jq] = mfma16(pf1, vf1, oacc[jq]);
    }
  }

  // l reduction: quad-reduce in-wave, then across waves via LDS
#pragma unroll
  for (int jq = 0; jq < 4; ++jq) {
    ls[jq] += __shfl_xor(ls[jq], 16);
    ls[jq] += __shfl_xor(ls[jq], 32);
  }
  if (quad == 0) {
#pragma unroll
    for (int jq = 0; jq < 4; ++jq) Lpart[w * 64 + 16 * jq + l15] = ls[jq];
  }
  __syncthreads();
  if (tid < 64)
    Lq[tid] = Lpart[tid] + Lpart[64 + tid] + Lpart[128 + tid] + Lpart[192 + tid];
  __syncthreads();

  // epilogue: O rows q = 16jq+4quad+r, cols d = 16w+l15; gate + store
#pragma unroll
  for (int jq = 0; jq < 4; ++jq) {
#pragma unroll
    for (int r = 0; r < 4; ++r) {
      int qloc = 16 * jq + 4 * quad + r;
      float lv = Lq[qloc];
      float gv = b2f(((const unsigned short*)gc)[
          ((size_t)((b * 16 + h) * 1024) + qt * 64 + qloc) * 64 + 16 * w + l15]);
      size_t row = (size_t)(b * NN + qt * 64 + qloc);
      gated[row * 1024 + h * 64 + 16 * w + l15] = f2b(oacc[jq][r] / lv * gv);
    }
  }
}

// ---------------------------------------------------------------------------
extern "C" void kernel_launch(void* const* d_in, const int* in_sizes, int n_in,
                              void* d_out, int out_size, void* d_ws,
                              size_t ws_size, hipStream_t stream) {
  const float* x = (const float*)d_in[0];
  const float* Wq = (const float*)d_in[1];
  const float* Wkv = (const float*)d_in[2];
  const float* Wg = (const float*)d_in[3];
  const float* bg = (const float*)d_in[4];
  const float* Wo = (const float*)d_in[5];
  float* out = (float*)d_out;

  // ws layout (short elems): ~36.6 MB total
  short* ws = (short*)d_ws;
  short* xb = ws;                     // 4.19M (x bf16; later aliased as gated)
  short* WcT = xb + 4194304;          // 2.62M (W^T combined: q|g|kv rows)
  short* WoT = WcT + 2621440;         // 1.05M
  short* qc = WoT + 1048576;          // 4.19M  q[b,h,tok,d]
  short* gc = qc + 4194304;           // 4.19M  gate[b,h,tok,d]
  short* kc = gc + 4194304;           // 1.05M  k[b,kvh,tok,d]
  short* vtw = kc + 1048576;          // 1.05M  v^T[b,kvh,d,tok]
  float* bias_f32 = (float*)(vtw + 1048576);  // 2560 f32

  dim3 blk(256);
  cvt_f32_bf16<<<4096, blk, 0, stream>>>(x, xb, 1048576);
  transpose_all<<<dim3(16, 16, 5), blk, 0, stream>>>(Wq, Wkv, Wg, Wo, bg, WcT,
                                                     WoT, bias_f32);
  // fused q|gate|kv projection (outputs diverted to compact layouts)
  gemm_proj<<<dim3(20, 32), blk, 0, stream>>>(xb, WcT, bias_f32, qc, gc, kc, vtw);
  // attention + gate -> gated (aliases xb; xb no longer needed)
  attn_mfma4<<<dim3(16, 64), blk, 0, stream>>>(qc, gc, kc, vtw, (unsigned short*)xb);
  // output projection
  gemm_out<<<dim3(8, 64), blk, 0, stream>>>(xb, WoT, out);
}

// Round 7
// 190.590 us; speedup vs baseline: 1.0144x; 1.0144x over previous
//
#include <hip/hip_runtime.h>
#include <hip/hip_bf16.h>
#include <stdint.h>

#define BB 4
#define NN 1024
#define DD 1024
#define HH 16
#define HDIM 64
#define KVHH 4
#define MM (BB * NN)  // 4096 token rows

typedef __hip_bfloat16 bf16;
typedef __attribute__((ext_vector_type(8))) short bf16x8;  // 8 bf16 = 4 VGPR
typedef __attribute__((ext_vector_type(4))) float f32x4;

__device__ __forceinline__ float b2f(unsigned short u) {
  return __uint_as_float(((unsigned)u) << 16);
}
__device__ __forceinline__ unsigned short f2b(float x) {
  bf16 h = __float2bfloat16(x);
  unsigned short u;
  __builtin_memcpy(&u, &h, 2);
  return u;
}
__device__ __forceinline__ f32x4 mfma16(bf16x8 a, bf16x8 b, f32x4 c) {
  return __builtin_amdgcn_mfma_f32_16x16x32_bf16(a, b, c, 0, 0, 0);
}
__device__ __forceinline__ void gl_lds16(const short* g, short* l) {
  __builtin_amdgcn_global_load_lds(
      (const __attribute__((address_space(1))) unsigned*)g,
      (__attribute__((address_space(3))) unsigned*)l, 16, 0, 0);
}

// ---------------------------------------------------------------------------
// z=0..3: weight transposes W (K x N fp32) -> WT (N x K bf16), 64x64 tiles.
// z=4: combined bias build. z=5: x fp32 -> bf16 convert.
// ---------------------------------------------------------------------------
__global__ __launch_bounds__(256) void transpose_all(
    const float* __restrict__ Wq, const float* __restrict__ Wkv,
    const float* __restrict__ Wg, const float* __restrict__ Wo,
    const float* __restrict__ bg, const float* __restrict__ x,
    short* __restrict__ WcT, short* __restrict__ WoT,
    float* __restrict__ bias, short* __restrict__ xb) {
  const int z = blockIdx.z;
  if (z == 4) {  // combined bias: [0,1024)=0, [1024,2048)=bg, [2048,2560)=0
    if (blockIdx.y == 0 && blockIdx.x < 10) {
      int i = blockIdx.x * 256 + threadIdx.x;
      if (i < 2560) bias[i] = (i >= 1024 && i < 2048) ? bg[i - 1024] : 0.f;
    }
    return;
  }
  if (z == 5) {  // x convert: 256 blocks x 256 threads x 16 float4
    int base = (blockIdx.y * 16 + blockIdx.x) * 256 + threadIdx.x;
#pragma unroll
    for (int it = 0; it < 16; ++it) {
      int i = base + it * 65536;
      float4 v = *(const float4*)&x[(size_t)i * 4];
      ushort4 o;
      o.x = f2b(v.x); o.y = f2b(v.y); o.z = f2b(v.z); o.w = f2b(v.w);
      *(ushort4*)&xb[(size_t)i * 4] = o;
    }
    return;
  }
  const float* W;
  short* WT;
  int N = 1024;
  const int K = 1024;
  if (z == 0) { W = Wq; WT = WcT; }
  else if (z == 1) { W = Wg; WT = WcT + 1048576; }
  else if (z == 2) {
    W = Wkv; WT = WcT + 2097152; N = 512;
    if (blockIdx.x >= 8) return;  // uniform early-out, before any sync
  } else { W = Wo; WT = WoT; }

  __shared__ short T[64 * 68];
  const int tid = threadIdx.x;
  const int n0 = blockIdx.x * 64, k0 = blockIdx.y * 64;
  {
    int i0 = tid >> 4, j4 = (tid & 15) * 4;
#pragma unroll
    for (int ii = 0; ii < 4; ++ii) {
      int i = i0 + 16 * ii;
      float4 w = *(const float4*)&W[(size_t)(k0 + i) * N + n0 + j4];
      ushort4 o;
      o.x = f2b(w.x); o.y = f2b(w.y); o.z = f2b(w.z); o.w = f2b(w.w);
      *(ushort4*)&T[i * 68 + j4] = o;
    }
  }
  __syncthreads();
  {
    int n = tid >> 2, k16 = (tid & 3) * 16;
    short tmp[16];
#pragma unroll
    for (int kk = 0; kk < 16; ++kk) tmp[kk] = T[(k16 + kk) * 68 + n];
    short* dst = WT + (size_t)(n0 + n) * K + k0 + k16;
#pragma unroll
    for (int s = 0; s < 16; s += 4) *(ushort4*)&dst[s] = *(const ushort4*)&tmp[s];
  }
}

// ---------------------------------------------------------------------------
// Fused projection GEMM: 64x128 tile (grid 20x64 = 1280 blocks = 5/CU), BK=32,
// double-buffered gl_lds. 4 waves = 2x2 of (32m x 64n). Epilogue diverts to
// compact head-major buffers:
//   q (col<1024) -> qc[b,h,tok,d] ; g (1024..2048) -> gc[b,h,tok,d]
//   k (2048..2304) -> kc[b,kvh,tok,d] ; v (2304..2560) -> vt[b,kvh,d,tok]
// ---------------------------------------------------------------------------
__global__ __launch_bounds__(256, 5) void gemm_proj(
    const short* __restrict__ A, const short* __restrict__ WT,
    const float* __restrict__ bias, short* __restrict__ qc,
    short* __restrict__ gc, short* __restrict__ kc, short* __restrict__ vt) {
  __shared__ short As[2][64 * 32];
  __shared__ short Bs[2][128 * 32];
  const int tid = threadIdx.x;
  const int wave = tid >> 6, lane = tid & 63, l15 = lane & 15, quad = lane >> 4;
  const int m0 = blockIdx.y * 64, n0 = blockIdx.x * 128;
  const int wm = (wave & 1) * 32, wn = (wave >> 1) * 64;
  const int arow = tid >> 2, ac = (tid & 3) * 8;
  const short* asrc = A + (size_t)(m0 + arow) * 1024 + ac;
  const short* bsrc = WT + (size_t)(n0 + arow) * 1024 + ac;

  gl_lds16(asrc, &As[0][wave * 512]);
  gl_lds16(bsrc, &Bs[0][wave * 512]);
  gl_lds16(bsrc + 64 * 1024, &Bs[0][wave * 512 + 2048]);

  f32x4 acc[2][4] = {};
  for (int k = 0; k < 32; ++k) {
    const int cur = k & 1;
    __syncthreads();  // stage(k) landed; iter k-1 LDS reads drained
    if (k < 31) {
      const short* ap = asrc + (k + 1) * 32;
      const short* bp = bsrc + (k + 1) * 32;
      gl_lds16(ap, &As[1 - cur][wave * 512]);
      gl_lds16(bp, &Bs[1 - cur][wave * 512]);
      gl_lds16(bp + 64 * 1024, &Bs[1 - cur][wave * 512 + 2048]);
    }
    bf16x8 af[2], bfr[4];
#pragma unroll
    for (int i = 0; i < 2; ++i)
      af[i] = *(const bf16x8*)&As[cur][(wm + 16 * i + l15) * 32 + quad * 8];
#pragma unroll
    for (int j = 0; j < 4; ++j)
      bfr[j] = *(const bf16x8*)&Bs[cur][(wn + 16 * j + l15) * 32 + quad * 8];
#pragma unroll
    for (int i = 0; i < 2; ++i)
#pragma unroll
      for (int j = 0; j < 4; ++j) acc[i][j] = mfma16(af[i], bfr[j], acc[i][j]);
  }
#pragma unroll
  for (int j = 0; j < 4; ++j) {
    int col = n0 + wn + 16 * j + l15;
    float bv = bias[col];
    int reg = col >> 6;  // head-slot 0..39 (uniform across the 16 lanes)
    int d = col & 63;
#pragma unroll
    for (int i = 0; i < 2; ++i) {
#pragma unroll
      for (int r = 0; r < 4; ++r) {
        int row = m0 + wm + 16 * i + quad * 4 + r;
        int b = row >> 10, tok = row & 1023;
        unsigned short v = f2b(acc[i][j][r] + bv);
        if (reg < 16)
          ((unsigned short*)qc)[((size_t)((b * 16 + reg) * 1024 + tok)) * 64 + d] = v;
        else if (reg < 32)
          ((unsigned short*)gc)[((size_t)((b * 16 + reg - 16) * 1024 + tok)) * 64 + d] = v;
        else if (reg < 36)
          ((unsigned short*)kc)[((size_t)((b * 4 + reg - 32) * 1024 + tok)) * 64 + d] = v;
        else
          ((unsigned short*)vt)[((size_t)((b * 4 + reg - 36) * 64 + d)) * 1024 + tok] = v;
      }
    }
  }
}

// ---------------------------------------------------------------------------
// Output-projection GEMM: 64x64 tile (grid 16x64 = 1024 blocks = 4/CU), BK=32,
// double-buffered. 4 waves = 2x2 of (32m x 32n).
// ---------------------------------------------------------------------------
__global__ __launch_bounds__(256, 4) void gemm_out(
    const short* __restrict__ A, const short* __restrict__ WT,
    float* __restrict__ Cout) {
  __shared__ short As[2][64 * 32];
  __shared__ short Bs[2][64 * 32];
  const int tid = threadIdx.x;
  const int wave = tid >> 6, lane = tid & 63, l15 = lane & 15, quad = lane >> 4;
  const int m0 = blockIdx.y * 64, n0 = blockIdx.x * 64;
  const int wm = (wave & 1) * 32, wn = (wave >> 1) * 32;
  const int arow = tid >> 2, ac = (tid & 3) * 8;
  const short* asrc = A + (size_t)(m0 + arow) * 1024 + ac;
  const short* bsrc = WT + (size_t)(n0 + arow) * 1024 + ac;

  gl_lds16(asrc, &As[0][wave * 512]);
  gl_lds16(bsrc, &Bs[0][wave * 512]);

  f32x4 acc[2][2] = {};
  for (int k = 0; k < 32; ++k) {
    const int cur = k & 1;
    __syncthreads();
    if (k < 31) {
      gl_lds16(asrc + (k + 1) * 32, &As[1 - cur][wave * 512]);
      gl_lds16(bsrc + (k + 1) * 32, &Bs[1 - cur][wave * 512]);
    }
    bf16x8 af[2], bfr[2];
#pragma unroll
    for (int i = 0; i < 2; ++i)
      af[i] = *(const bf16x8*)&As[cur][(wm + 16 * i + l15) * 32 + quad * 8];
#pragma unroll
    for (int j = 0; j < 2; ++j)
      bfr[j] = *(const bf16x8*)&Bs[cur][(wn + 16 * j + l15) * 32 + quad * 8];
#pragma unroll
    for (int i = 0; i < 2; ++i)
#pragma unroll
      for (int j = 0; j < 2; ++j) acc[i][j] = mfma16(af[i], bfr[j], acc[i][j]);
  }
#pragma unroll
  for (int j = 0; j < 2; ++j) {
    int col = n0 + wn + 16 * j + l15;
#pragma unroll
    for (int i = 0; i < 2; ++i) {
#pragma unroll
      for (int r = 0; r < 4; ++r) {
        int row = m0 + wm + 16 * i + quad * 4 + r;
        Cout[(size_t)row * 1024 + col] = acc[i][j][r];
      }
    }
  }
}

// ---------------------------------------------------------------------------
// MFMA flash attention + gate. S^T formulation, fixed-max softmax, compact
// head-major inputs, SINGLE-buffered swizzled K/V staging (25 KB LDS ->
// 6 blocks/CU; block-level TLP hides staging latency). 3 barriers/kt.
// Block: (qt, b*16+h), 64 q rows, 4 waves; wave owns 16 keys (S) / 16 d (PV).
// ---------------------------------------------------------------------------
__global__ __launch_bounds__(256, 6) void attn_mfma5(
    const short* __restrict__ qc, const short* __restrict__ gc,
    const short* __restrict__ kc, const short* __restrict__ vt,
    unsigned short* __restrict__ gated) {
  __shared__ short Kt[64 * 64];
  __shared__ short Vt[64 * 64];
  __shared__ short Ps[64 * 64];
  __shared__ float Lpart[4 * 64];
  __shared__ float Lq[64];
  const int tid = threadIdx.x;
  const int w = tid >> 6, lane = tid & 63, l15 = lane & 15, quad = lane >> 4;
  const int qt = blockIdx.x, bh = blockIdx.y, b = bh >> 4, h = bh & 15, kvh = h >> 2;
  const int fs = l15 & 7;                // frag-read swizzle key (row&7)
  const int s0 = (quad ^ fs) * 8;        // slot offset, k-chunk quad
  const int s1 = ((4 + quad) ^ fs) * 8;  // slot offset, k-chunk 4+quad

  // Q B-frags (loop-invariant); qc rows are 128 B apart
  bf16x8 qf[4][2];
#pragma unroll
  for (int jq = 0; jq < 4; ++jq) {
    const short* qp =
        qc + ((size_t)((b * 16 + h) * 1024) + qt * 64 + 16 * jq + l15) * 64 + quad * 8;
    qf[jq][0] = *(const bf16x8*)qp;
    qf[jq][1] = *(const bf16x8*)(qp + 32);
  }

  // staging: lane covers (row = 16w + srow + 8i, chunk = schunk); contiguous 2KB
  const int srow = lane >> 3;
  const int schunk = (lane & 7) ^ srow;
  const short* kstage = kc + ((size_t)((b * 4 + kvh) * 1024) + 16 * w + srow) * 64 + schunk * 8;
  const short* vstage = vt + ((size_t)((b * 4 + kvh) * 64) + 16 * w + srow) * 1024 + schunk * 8;

  f32x4 oacc[4];
  float ls[4];
#pragma unroll
  for (int jq = 0; jq < 4; ++jq) {
    oacc[jq] = (f32x4){0.f, 0.f, 0.f, 0.f};
    ls[jq] = 0.f;
  }

  // P-write slot: uint2 = keys [16w+4quad,+4) -> chunk 2w+(quad>>1), half quad&1
  const int pslot = ((2 * w + (quad >> 1)) ^ fs) * 8 + (quad & 1) * 4;

  for (int kt = 0; kt < 16; ++kt) {
    __syncthreads();  // prior S K-reads and PV V-reads drained
    {
      const short* kp = kstage + (size_t)kt * 4096;
      const short* vp = vstage + (size_t)kt * 64;
      gl_lds16(kp, &Kt[(16 * w) * 64]);
      gl_lds16(kp + 512, &Kt[(16 * w + 8) * 64]);
      gl_lds16(vp, &Vt[(16 * w) * 64]);
      gl_lds16(vp + 8192, &Vt[(16 * w + 8) * 64]);
    }
    __syncthreads();  // K/V(kt) staged (vmcnt drained at barrier)
    // ---- S phase: S^T = K·Q^T, wave owns keys [16w,16w+16)
    bf16x8 kf0 = *(const bf16x8*)&Kt[(16 * w + l15) * 64 + s0];
    bf16x8 kf1 = *(const bf16x8*)&Kt[(16 * w + l15) * 64 + s1];
#pragma unroll
    for (int jq = 0; jq < 4; ++jq) {
      f32x4 st = mfma16(kf0, qf[jq][0], (f32x4){0.f, 0.f, 0.f, 0.f});
      st = mfma16(kf1, qf[jq][1], st);
      float p0 = __expf(st[0] * 0.125f);
      float p1 = __expf(st[1] * 0.125f);
      float p2 = __expf(st[2] * 0.125f);
      float p3 = __expf(st[3] * 0.125f);
      ls[jq] += (p0 + p1) + (p2 + p3);
      uint2 dd;
      dd.x = (unsigned)f2b(p0) | ((unsigned)f2b(p1) << 16);
      dd.y = (unsigned)f2b(p2) | ((unsigned)f2b(p3) << 16);
      *(uint2*)&Ps[(16 * jq + l15) * 64 + pslot] = dd;
    }
    __syncthreads();  // P(kt) visible
    // ---- PV phase: wave owns d-subtile w
    bf16x8 vf0 = *(const bf16x8*)&Vt[(16 * w + l15) * 64 + s0];
    bf16x8 vf1 = *(const bf16x8*)&Vt[(16 * w + l15) * 64 + s1];
#pragma unroll
    for (int jq = 0; jq < 4; ++jq) {
      bf16x8 pf0 = *(const bf16x8*)&Ps[(16 * jq + l15) * 64 + s0];
      bf16x8 pf1 = *(const bf16x8*)&Ps[(16 * jq + l15) * 64 + s1];
      oacc[jq] = mfma16(pf0, vf0, oacc[jq]);
      oacc[jq] = mfma16(pf1, vf1, oacc[jq]);
    }
  }

  // l reduction: quad-reduce in-wave, then across waves via LDS
#pragma unroll
  for (int jq = 0; jq < 4; ++jq) {
    ls[jq] += __shfl_xor(ls[jq], 16);
    ls[jq] += __shfl_xor(ls[jq], 32);
  }
  if (quad == 0) {
#pragma unroll
    for (int jq = 0; jq < 4; ++jq) Lpart[w * 64 + 16 * jq + l15] = ls[jq];
  }
  __syncthreads();
  if (tid < 64)
    Lq[tid] = Lpart[tid] + Lpart[64 + tid] + Lpart[128 + tid] + Lpart[192 + tid];
  __syncthreads();

  // epilogue: O rows q = 16jq+4quad+r, cols d = 16w+l15; gate + store
#pragma unroll
  for (int jq = 0; jq < 4; ++jq) {
#pragma unroll
    for (int r = 0; r < 4; ++r) {
      int qloc = 16 * jq + 4 * quad + r;
      float lv = Lq[qloc];
      float gv = b2f(((const unsigned short*)gc)[
          ((size_t)((b * 16 + h) * 1024) + qt * 64 + qloc) * 64 + 16 * w + l15]);
      size_t row = (size_t)(b * NN + qt * 64 + qloc);
      gated[row * 1024 + h * 64 + 16 * w + l15] = f2b(oacc[jq][r] / lv * gv);
    }
  }
}

// ---------------------------------------------------------------------------
extern "C" void kernel_launch(void* const* d_in, const int* in_sizes, int n_in,
                              void* d_out, int out_size, void* d_ws,
                              size_t ws_size, hipStream_t stream) {
  const float* x = (const float*)d_in[0];
  const float* Wq = (const float*)d_in[1];
  const float* Wkv = (const float*)d_in[2];
  const float* Wg = (const float*)d_in[3];
  const float* bg = (const float*)d_in[4];
  const float* Wo = (const float*)d_in[5];
  float* out = (float*)d_out;

  // ws layout (short elems): ~36.6 MB total
  short* ws = (short*)d_ws;
  short* xb = ws;                     // 4.19M (x bf16; later aliased as gated)
  short* WcT = xb + 4194304;          // 2.62M (W^T combined: q|g|kv rows)
  short* WoT = WcT + 2621440;         // 1.05M
  short* qc = WoT + 1048576;          // 4.19M  q[b,h,tok,d]
  short* gc = qc + 4194304;           // 4.19M  gate[b,h,tok,d]
  short* kc = gc + 4194304;           // 1.05M  k[b,kvh,tok,d]
  short* vtw = kc + 1048576;          // 1.05M  v^T[b,kvh,d,tok]
  float* bias_f32 = (float*)(vtw + 1048576);  // 2560 f32

  dim3 blk(256);
  // weight transposes + bias + x-convert, one dispatch
  transpose_all<<<dim3(16, 16, 6), blk, 0, stream>>>(Wq, Wkv, Wg, Wo, bg, x,
                                                     WcT, WoT, bias_f32, xb);
  // fused q|gate|kv projection (outputs diverted to compact layouts)
  gemm_proj<<<dim3(20, 64), blk, 0, stream>>>(xb, WcT, bias_f32, qc, gc, kc, vtw);
  // attention + gate -> gated (aliases xb; xb no longer needed)
  attn_mfma5<<<dim3(16, 64), blk, 0, stream>>>(qc, gc, kc, vtw, (unsigned short*)xb);
  // output projection
  gemm_out<<<dim3(16, 64), blk, 0, stream>>>(xb, WoT, out);
}